// Round 7
// baseline (3441.632 us; speedup 1.0000x reference)
//
#include <hip/hip_runtime.h>
#include <hip/hip_bf16.h>

#define NSTEPS 100
#define DT (1.0f / 100.0f)
#define TSCALE 2.885390081777927f   // 2*log2(e): folded into W1,W2,b1,b2

typedef __attribute__((ext_vector_type(8))) short short8;   // 8 bf16 (MFMA A/B frag)
typedef __attribute__((ext_vector_type(4))) float floatx4;  // MFMA C/D frag

__device__ __forceinline__ unsigned short f2bf(float f) {
  union { float f; unsigned int u; } v; v.f = f;
  unsigned int u = v.u;
  return (unsigned short)((u + 0x7fffu + ((u >> 16) & 1u)) >> 16);  // RNE
}
__device__ __forceinline__ unsigned int pk2(float a, float b) {
  __hip_bfloat162 h = __float22bfloat162_rn(make_float2(a, b));
  union { __hip_bfloat162 h; unsigned int u; } v; v.h = h;
  return v.u;
}
// tanh with input pre-scaled by 2*log2(e): tanh = 1 - 2/(2^y + 1)
__device__ __forceinline__ float tanh_pre(float y) {
  float e = __builtin_amdgcn_exp2f(y);
  return 1.0f - 2.0f * __builtin_amdgcn_rcpf(e + 1.0f);
}

// Repack W (K x N row-major fp32) into frag-major bf16 (A-frag of W^T).
// W1/W2 are pre-scaled by TSCALE (tanh input scale folded in).
// (R6's jj^4 compensation REVERTED — it was mathematically unsound.)
__global__ void prep_weights(const float* __restrict__ W1,
                             const float* __restrict__ W2,
                             const float* __restrict__ W3,
                             unsigned short* __restrict__ ws) {
  int e = blockIdx.x * 256 + threadIdx.x;  // 98304 total
  const float* src; int N, ntile, el, base; float sc;
  if (e < 16384)      { src = W1; N = 256; ntile = 16; base = 0;     el = e;         sc = TSCALE; }
  else if (e < 81920) { src = W2; N = 256; ntile = 16; base = 16384; el = e - 16384; sc = TSCALE; }
  else                { src = W3; N = 64;  ntile = 4;  base = 81920; el = e - 81920; sc = 1.0f; }
  int j = el & 7;
  int l = (el >> 3) & 63;
  int rem = el >> 9;
  int t = rem % ntile;
  int s = rem / ntile;
  int k = s * 32 + ((l >> 4) << 3) + j;
  int n = t * 16 + (l & 15);
  ws[base + el] = f2bf(src[k * N + n] * sc);
}

// R7 = R2/R5 baseline (5-phase dual-group, weights register-resident)
// + P3 read de-amplification: P3 wave ownership re-decomposed from
// (1 M-tile x 2 col-tiles) to (2 M-tiles x 1 col-tile), so each H2
// B-frag read feeds 2 MFMAs instead of 1. P3 LDS reads halve 16->8
// per group; total b128 reads/wave-iter 112->96 on an ~86%-busy LDS
// pipe. w3f doubles to 16 frags (+32 VGPR); Zbuf k_dim mapping stays
// identity under the (mp,nc) parameterization so prep is unchanged.
__global__ __launch_bounds__(512, 2)
void cnf_kernel(const float* __restrict__ z0,
                const float* __restrict__ b1,
                const float* __restrict__ b2,
                const float* __restrict__ b3,
                const unsigned short* __restrict__ wsAll,
                float* __restrict__ out) {
  extern __shared__ unsigned short smem[];   // 81920 B
  unsigned short* ZbufA = smem;              //  8192 B (4 nt * 2 s * 512)
  unsigned short* ZbufB = smem + 4096;
  unsigned short* HbufA = smem + 8192;       // 32768 B (4 nt * 8 s * 512)
  unsigned short* HbufB = smem + 24576;

  const int tid  = threadIdx.x;
  const int wave = tid >> 6;
  const int lane = tid & 63;
  const int i15  = lane & 15;
  const int q    = lane >> 4;
  const int grow = blockIdx.x * 128;         // group A rows; B = +64
  const int mp   = wave >> 2;                // L3 M-pair (dim tiles 2mp, 2mp+1)
  const int nc   = wave & 3;                 // L3 col-tile

  const unsigned short* wsW1 = wsAll;
  const unsigned short* wsW2 = wsAll + 16384;
  const unsigned short* wsW3 = wsAll + 81920;

  // ---- register-resident weight A-frags ----
  // W1: per wave its 2 hid-tiles x 2 K-slices = 4 frags (16 VGPR)
  short8 w1f[2][2];
#pragma unroll
  for (int s = 0; s < 2; ++s)
#pragma unroll
    for (int tt = 0; tt < 2; ++tt)
      w1f[s][tt] = *(const short8*)&wsW1[((s * 16 + 2 * wave + tt) * 64 + lane) * 8];
  // W2: 16 frags (64 VGPR)
  short8 w2f[8][2];
#pragma unroll
  for (int s = 0; s < 8; ++s)
#pragma unroll
    for (int tt = 0; tt < 2; ++tt)
      w2f[s][tt] = *(const short8*)&wsW2[((s * 16 + 2 * wave + tt) * 64 + lane) * 8];
  // W3: per wave its M-PAIR x 8 K-slices = 16 frags (64 VGPR)
  short8 w3f[2][8];
#pragma unroll
  for (int jm = 0; jm < 2; ++jm)
#pragma unroll
    for (int s = 0; s < 8; ++s)
      w3f[jm][s] = *(const short8*)&wsW3[((s * 4 + 2 * mp + jm) * 64 + lane) * 8];

  // ---- bias C-frags (fp32); b1/b2 pre-scaled by TSCALE ----
  floatx4 b1f[2], b2f[2], b3f[2];
#pragma unroll
  for (int tt = 0; tt < 2; ++tt) {
    float4 v1 = *(const float4*)&b1[(2 * wave + tt) * 16 + q * 4];
    float4 v2 = *(const float4*)&b2[(2 * wave + tt) * 16 + q * 4];
    b1f[tt] = floatx4{v1.x * TSCALE, v1.y * TSCALE, v1.z * TSCALE, v1.w * TSCALE};
    b2f[tt] = floatx4{v2.x * TSCALE, v2.y * TSCALE, v2.z * TSCALE, v2.w * TSCALE};
  }
#pragma unroll
  for (int jm = 0; jm < 2; ++jm) {
    float4 v3 = *(const float4*)&b3[(2 * mp + jm) * 16 + q * 4];
    b3f[jm] = floatx4{v3.x, v3.y, v3.z, v3.w};
  }

  // ---- frag-layout index bases ----
  const int rb  = lane * 8;                                   // act read base; tile adds *512
  const int j0  = 4 * (q & 1);
  const int hw0 = (wave * 64 + i15 + 16 * (q >> 1)) * 8 + j0; // +tt*256, +nt*4096
  // Zbuf write base for dim-tile (2mp+jm): subtile = nc*1024 + mp*512,
  // row = i15 + 16*(2*jm + (q>>1)), half j0.  k_dim mapping stays identity.
  const int zw0 = nc * 1024 + (mp * 64 + i15) * 8 + j0;       // + (2*jm + (q>>1))*128

  // ---- RK4 state, both groups ----
  // zA[jm*4+r]: dim-tile 2mp+jm, slot q*4+r, batch col nc*16+i15
  float zA[8], zaccA[8], zB[8], zaccB[8];
#pragma unroll
  for (int jm = 0; jm < 2; ++jm) {
    float4 va = *(const float4*)&z0[(grow + nc * 16 + i15) * 64 + (2 * mp + jm) * 16 + q * 4];
    float4 vb = *(const float4*)&z0[(grow + 64 + nc * 16 + i15) * 64 + (2 * mp + jm) * 16 + q * 4];
    zA[jm*4+0]=va.x; zA[jm*4+1]=va.y; zA[jm*4+2]=va.z; zA[jm*4+3]=va.w;
    zB[jm*4+0]=vb.x; zB[jm*4+1]=vb.y; zB[jm*4+2]=vb.z; zB[jm*4+3]=vb.w;
#pragma unroll
    for (int r = 0; r < 4; ++r) { zaccA[jm*4+r] = 0.f; zaccB[jm*4+r] = 0.f; }
    uint2 pa; pa.x = pk2(va.x, va.y); pa.y = pk2(va.z, va.w);
    uint2 pb; pb.x = pk2(vb.x, vb.y); pb.y = pk2(vb.z, vb.w);
    const int zw = zw0 + (2 * jm + (q >> 1)) * 128;
    *(uint2*)&ZbufA[zw] = pa;
    *(uint2*)&ZbufB[zw] = pb;
  }

  const float DT6 = DT / 6.0f, DT3 = DT / 3.0f, DTH = 0.5f * DT;

  floatx4 accA[2][4], accB[2][4];

  // ---- helpers ----
  // one-eighth of an epilogue: 4 tanh + 2 packs + 1 b64 write
  auto ePart = [&](int u, floatx4 (&a)[2][4], unsigned short* H) {
    const int tt = u >> 2, nt = u & 3;
    uint2 p;
    p.x = pk2(tanh_pre(a[tt][nt][0]), tanh_pre(a[tt][nt][1]));
    p.y = pk2(tanh_pre(a[tt][nt][2]), tanh_pre(a[tt][nt][3]));
    *(uint2*)&H[hw0 + tt * 256 + nt * 4096] = p;
  };
  // one step of L1 (pair u: s=u>>2, nt=u&3): 2 MFMAs; s==0 seeds bias-C
  auto p1Step = [&](int u, const unsigned short* Z, floatx4 (&a)[2][4]) {
    const int s = u >> 2, nt = u & 3;
    short8 bz = *(const short8*)&Z[rb + (nt * 2 + s) * 512];
    if (s == 0) {
      a[0][nt] = __builtin_amdgcn_mfma_f32_16x16x32_bf16(w1f[0][0], bz, b1f[0], 0, 0, 0);
      a[1][nt] = __builtin_amdgcn_mfma_f32_16x16x32_bf16(w1f[0][1], bz, b1f[1], 0, 0, 0);
    } else {
      a[0][nt] = __builtin_amdgcn_mfma_f32_16x16x32_bf16(w1f[1][0], bz, a[0][nt], 0, 0, 0);
      a[1][nt] = __builtin_amdgcn_mfma_f32_16x16x32_bf16(w1f[1][1], bz, a[1][nt], 0, 0, 0);
    }
  };
  // one s-step of L3: ONE B-read feeds 2 MFMAs (M-pair); s==0 seeds bias-C
  auto p3Step = [&](int s, const unsigned short* H, floatx4 (&a3)[2]) {
    short8 bh = *(const short8*)&H[rb + (nc * 8 + s) * 512];
    if (s == 0) {
      a3[0] = __builtin_amdgcn_mfma_f32_16x16x32_bf16(w3f[0][0], bh, b3f[0], 0, 0, 0);
      a3[1] = __builtin_amdgcn_mfma_f32_16x16x32_bf16(w3f[1][0], bh, b3f[1], 0, 0, 0);
    } else {
      a3[0] = __builtin_amdgcn_mfma_f32_16x16x32_bf16(w3f[0][s], bh, a3[0], 0, 0, 0);
      a3[1] = __builtin_amdgcn_mfma_f32_16x16x32_bf16(w3f[1][s], bh, a3[1], 0, 0, 0);
    }
  };
  auto rk4Tail = [&](floatx4 (&a3)[2], float (&z)[8], float (&zacc)[8],
                     unsigned short* Z, int st) {
    const float wsum  = (st == 0 || st == 3) ? DT6 : DT3;
    const float cst   = (st == 2) ? DT : DTH;
    const bool  last  = (st == 3);
    const bool  first = (st == 0);
#pragma unroll
    for (int jm = 0; jm < 2; ++jm) {
      float stg[4];
#pragma unroll
      for (int r = 0; r < 4; ++r) {
        const int i = jm * 4 + r;
        float k = a3[jm][r];
        float za = first ? z[i] : zacc[i];
        za += wsum * k;
        zacc[i] = za;
        if (last) { z[i] = za; stg[r] = za; }
        else      { stg[r] = z[i] + cst * k; }
      }
      uint2 p; p.x = pk2(stg[0], stg[1]); p.y = pk2(stg[2], stg[3]);
      *(uint2*)&Z[zw0 + (2 * jm + (q >> 1)) * 128] = p;
    }
  };

  // ---- prologue: advance B through P1,E1,P2,E2 of stage 0 (unfused) ----
  __syncthreads();                 // Zbuf init visible
#pragma unroll
  for (int u = 0; u < 8; ++u) p1Step(u, ZbufB, accB);
#pragma unroll
  for (int u = 0; u < 8; ++u) ePart(u, accB, HbufB);
  __syncthreads();
#pragma unroll
  for (int s = 0; s < 8; ++s)
#pragma unroll
    for (int nt = 0; nt < 4; ++nt) {
      short8 bh = *(const short8*)&HbufB[rb + (nt * 8 + s) * 512];
      accB[0][nt] = __builtin_amdgcn_mfma_f32_16x16x32_bf16(w2f[s][0], bh,
                      s == 0 ? b2f[0] : accB[0][nt], 0, 0, 0);
      accB[1][nt] = __builtin_amdgcn_mfma_f32_16x16x32_bf16(w2f[s][1], bh,
                      s == 0 ? b2f[1] : accB[1][nt], 0, 0, 0);
    }
  __syncthreads();
#pragma unroll
  for (int u = 0; u < 8; ++u) ePart(u, accB, HbufB);
  __syncthreads();

  // ---- steady state: 5 intervals per it, MFMA⇄VALU fused per step ----
#pragma unroll 1
  for (int it = 0; it < NSTEPS * 4; ++it) {
    const int st = it & 3;

    // k=0: A:P1 (16 MFMA) fused with B:P3 (16 MFMA) + B RK4 tail
    {
      floatx4 a3[2];
#pragma unroll
      for (int u = 0; u < 8; ++u) {
        p3Step(u, HbufB, a3);
        p1Step(u, ZbufA, accA);
      }
      rk4Tail(a3, zB, zaccB, ZbufB, st);
    }
    __syncthreads();

    // k=1: B:P1 (16 MFMA) fused with A:E1 (32 tanh)
    {
#pragma unroll
      for (int u = 0; u < 8; ++u) {
        p1Step(u, ZbufB, accB);
        ePart(u, accA, HbufA);
      }
    }
    __syncthreads();

    // k=2: A:P2 (64 MFMA) fused with B:E1 (32 tanh)
    {
#pragma unroll
      for (int s = 0; s < 8; ++s) {
#pragma unroll
        for (int nt = 0; nt < 4; ++nt) {
          short8 bh = *(const short8*)&HbufA[rb + (nt * 8 + s) * 512];
          accA[0][nt] = __builtin_amdgcn_mfma_f32_16x16x32_bf16(w2f[s][0], bh,
                          s == 0 ? b2f[0] : accA[0][nt], 0, 0, 0);
          accA[1][nt] = __builtin_amdgcn_mfma_f32_16x16x32_bf16(w2f[s][1], bh,
                          s == 0 ? b2f[1] : accA[1][nt], 0, 0, 0);
        }
        ePart(s, accB, HbufB);
      }
    }
    __syncthreads();

    // k=3: B:P2 (64 MFMA) fused with A:E2 (32 tanh)
    {
#pragma unroll
      for (int s = 0; s < 8; ++s) {
#pragma unroll
        for (int nt = 0; nt < 4; ++nt) {
          short8 bh = *(const short8*)&HbufB[rb + (nt * 8 + s) * 512];
          accB[0][nt] = __builtin_amdgcn_mfma_f32_16x16x32_bf16(w2f[s][0], bh,
                          s == 0 ? b2f[0] : accB[0][nt], 0, 0, 0);
          accB[1][nt] = __builtin_amdgcn_mfma_f32_16x16x32_bf16(w2f[s][1], bh,
                          s == 0 ? b2f[1] : accB[1][nt], 0, 0, 0);
        }
        ePart(s, accA, HbufA);
      }
    }
    __syncthreads();

    // k=4: A:P3 (16 MFMA) + A RK4, fused with B:E2 (32 tanh)
    {
      floatx4 a3[2];
#pragma unroll
      for (int u = 0; u < 8; ++u) {
        p3Step(u, HbufA, a3);
        ePart(u, accB, HbufB);
      }
      rk4Tail(a3, zA, zaccA, ZbufA, st);
    }
    __syncthreads();
  }
  // (B's trailing stage-400 P1/P2/E work never runs P3, so zB is final.)

  // ---- final store, both groups ----
#pragma unroll
  for (int jm = 0; jm < 2; ++jm) {
    float4 va, vb;
    va.x = zA[jm*4+0]; va.y = zA[jm*4+1]; va.z = zA[jm*4+2]; va.w = zA[jm*4+3];
    vb.x = zB[jm*4+0]; vb.y = zB[jm*4+1]; vb.z = zB[jm*4+2]; vb.w = zB[jm*4+3];
    *(float4*)&out[(grow + nc * 16 + i15) * 64 + (2 * mp + jm) * 16 + q * 4] = va;
    *(float4*)&out[(grow + 64 + nc * 16 + i15) * 64 + (2 * mp + jm) * 16 + q * 4] = vb;
  }
}

extern "C" void kernel_launch(void* const* d_in, const int* in_sizes, int n_in,
                              void* d_out, int out_size, void* d_ws, size_t ws_size,
                              hipStream_t stream) {
  const float* z0 = (const float*)d_in[0];
  const float* W1 = (const float*)d_in[1];
  const float* b1 = (const float*)d_in[2];
  const float* W2 = (const float*)d_in[3];
  const float* b2 = (const float*)d_in[4];
  const float* W3 = (const float*)d_in[5];
  const float* b3 = (const float*)d_in[6];
  unsigned short* ws = (unsigned short*)d_ws;  // 98304 bf16 = 196608 B

  prep_weights<<<384, 256, 0, stream>>>(W1, W2, W3, ws);
  (void)hipFuncSetAttribute((const void*)cnf_kernel,
                            hipFuncAttributeMaxDynamicSharedMemorySize, 81920);
  cnf_kernel<<<256, 512, 81920, stream>>>(z0, b1, b2, b3, ws, (float*)d_out);
}

// Round 8
// 2976.692 us; speedup vs baseline: 1.1562x; 1.1562x over previous
//
#include <hip/hip_runtime.h>
#include <hip/hip_bf16.h>

#define NSTEPS 100
#define DT (1.0f / 100.0f)
#define TSCALE 2.885390081777927f   // 2*log2(e): folded into W1,W2,b1,b2

typedef __attribute__((ext_vector_type(8))) short short8;   // 8 bf16 (MFMA A/B frag)
typedef __attribute__((ext_vector_type(4))) short short4v;  // 4 bf16 (8B half-frag)
typedef __attribute__((ext_vector_type(4))) float floatx4;  // MFMA C/D frag

__device__ __forceinline__ unsigned short f2bf(float f) {
  union { float f; unsigned int u; } v; v.f = f;
  unsigned int u = v.u;
  return (unsigned short)((u + 0x7fffu + ((u >> 16) & 1u)) >> 16);  // RNE
}
__device__ __forceinline__ unsigned int pk2(float a, float b) {
  __hip_bfloat162 h = __float22bfloat162_rn(make_float2(a, b));
  union { __hip_bfloat162 h; unsigned int u; } v; v.h = h;
  return v.u;
}
// tanh with input pre-scaled by 2*log2(e): tanh = 1 - 2/(2^y + 1)
__device__ __forceinline__ float tanh_pre(float y) {
  float e = __builtin_amdgcn_exp2f(y);
  return 1.0f - 2.0f * __builtin_amdgcn_rcpf(e + 1.0f);
}
// H-frag load from 8B-aligned (24B-line) Hbuf: two b64 halves -> short8
__device__ __forceinline__ short8 ldH(const unsigned short* p) {
  union { short8 v; short4v h[2]; } u;
  u.h[0] = *(const short4v*)p;
  u.h[1] = *(const short4v*)(p + 4);
  return u.v;
}

// Repack W (K x N row-major fp32) into frag-major bf16 (A-frag of W^T).
// W1/W2 are pre-scaled by TSCALE (tanh input scale folded in).
__global__ void prep_weights(const float* __restrict__ W1,
                             const float* __restrict__ W2,
                             const float* __restrict__ W3,
                             unsigned short* __restrict__ ws) {
  int e = blockIdx.x * 256 + threadIdx.x;  // 98304 total
  const float* src; int N, ntile, el, base; float sc;
  if (e < 16384)      { src = W1; N = 256; ntile = 16; base = 0;     el = e;         sc = TSCALE; }
  else if (e < 81920) { src = W2; N = 256; ntile = 16; base = 16384; el = e - 16384; sc = TSCALE; }
  else                { src = W3; N = 64;  ntile = 4;  base = 81920; el = e - 81920; sc = 1.0f; }
  int j = el & 7;
  int l = (el >> 3) & 63;
  int rem = el >> 9;
  int t = rem % ntile;
  int s = rem / ntile;
  int k = s * 32 + ((l >> 4) << 3) + j;
  int n = t * 16 + (l & 15);
  ws[base + el] = f2bf(src[k * N + n] * sc);
}

// R8 = R5 (5-phase dual-group, weights register-resident, 2642-2709 us)
// + Hbuf 24B-line layout. SQ_LDS_BANK_CONFLICT=1.181e8 is EXACTLY the 8B
// H/Z writes: 16-lane phases at 16B line stride hit banks 4*i15 mod 32
// (i15 and i15+8 collide -> 4 extra cyc/write). With 24B line stride the
// phase hits 6*i15+2H mod 32 = 16 distinct bank-pairs: conflict-free.
// Pure ADDRESS permutation (unlike R6): values unmoved, prep unchanged,
// numerics bit-identical. Cost: H-reads are 8B-aligned -> 2x ds_read_b64
// per frag (same bytes/pipe-cycles); Hbuf 32KB->48KB each (LDS 112KB,
// still 1 block/CU since occupancy is register-bound: R4/R7 showed the
// ~256-reg/wave wall; 8 waves x ~246 regs fill the 2048-reg pool).
// Zbuf (4 of 36 writes) stays plain: residual conflicts ~1.3e7.
__global__ __launch_bounds__(512, 2)
void cnf_kernel(const float* __restrict__ z0,
                const float* __restrict__ b1,
                const float* __restrict__ b2,
                const float* __restrict__ b3,
                const unsigned short* __restrict__ wsAll,
                float* __restrict__ out) {
  extern __shared__ unsigned short smem[];   // 114688 B
  unsigned short* ZbufA = smem;              // 8192 B: [nt4][s2][512]
  unsigned short* ZbufB = smem + 4096;
  unsigned short* HbufA = smem + 8192;       // 49152 B: [nt4][ss8][64 lines x 12]
  unsigned short* HbufB = smem + 32768;

  const int tid  = threadIdx.x;
  const int wave = tid >> 6;
  const int lane = tid & 63;
  const int i15  = lane & 15;
  const int q    = lane >> 4;
  const int grow = blockIdx.x * 128;         // group A rows; B = +64
  const int mt3  = wave & 3;                 // L3 M-tile
  const int ntp  = wave >> 2;                // L3 N-pair

  const unsigned short* wsW1 = wsAll;
  const unsigned short* wsW2 = wsAll + 16384;
  const unsigned short* wsW3 = wsAll + 81920;

  // ---- register-resident weight A-frags ----
  short8 w1f[2][2];
#pragma unroll
  for (int s = 0; s < 2; ++s)
#pragma unroll
    for (int tt = 0; tt < 2; ++tt)
      w1f[s][tt] = *(const short8*)&wsW1[((s * 16 + 2 * wave + tt) * 64 + lane) * 8];
  short8 w2f[8][2];
#pragma unroll
  for (int s = 0; s < 8; ++s)
#pragma unroll
    for (int tt = 0; tt < 2; ++tt)
      w2f[s][tt] = *(const short8*)&wsW2[((s * 16 + 2 * wave + tt) * 64 + lane) * 8];
  short8 w3f[8];
#pragma unroll
  for (int s = 0; s < 8; ++s)
    w3f[s] = *(const short8*)&wsW3[((s * 4 + mt3) * 64 + lane) * 8];

  // ---- bias C-frags (fp32); b1/b2 pre-scaled by TSCALE ----
  floatx4 b1f[2], b2f[2], b3f;
#pragma unroll
  for (int tt = 0; tt < 2; ++tt) {
    float4 v1 = *(const float4*)&b1[(2 * wave + tt) * 16 + q * 4];
    float4 v2 = *(const float4*)&b2[(2 * wave + tt) * 16 + q * 4];
    b1f[tt] = floatx4{v1.x * TSCALE, v1.y * TSCALE, v1.z * TSCALE, v1.w * TSCALE};
    b2f[tt] = floatx4{v2.x * TSCALE, v2.y * TSCALE, v2.z * TSCALE, v2.w * TSCALE};
  }
  {
    float4 v3 = *(const float4*)&b3[mt3 * 16 + q * 4];
    b3f = floatx4{v3.x, v3.y, v3.z, v3.w};
  }

  // ---- frag-layout index bases ----
  const int rb   = lane * 8;                                  // Zbuf read base (16B lines)
  const int rbH  = lane * 12;                                 // Hbuf read base (24B lines)
  const int j0   = 4 * (q & 1);
  // Hbuf write: granule (nt, ss=wave), line L = i15+16(q>>1)+32tt, half j0
  const int hw0  = wave * 768 + (i15 + 16 * (q >> 1)) * 12 + j0;  // +tt*384, +nt*6144
  const int zw0  = ((mt3 >> 1) * 64 + i15 + 16 * (2 * (mt3 & 1) + (q >> 1))) * 8 + j0;  // +nt*1024

  // ---- RK4 state, both groups ----
  float zA[8], zaccA[8], zB[8], zaccB[8];
#pragma unroll
  for (int j = 0; j < 2; ++j) {
    const int nt = 2 * ntp + j;
    float4 va = *(const float4*)&z0[(grow + nt * 16 + i15) * 64 + mt3 * 16 + q * 4];
    float4 vb = *(const float4*)&z0[(grow + 64 + nt * 16 + i15) * 64 + mt3 * 16 + q * 4];
    zA[j*4+0]=va.x; zA[j*4+1]=va.y; zA[j*4+2]=va.z; zA[j*4+3]=va.w;
    zB[j*4+0]=vb.x; zB[j*4+1]=vb.y; zB[j*4+2]=vb.z; zB[j*4+3]=vb.w;
#pragma unroll
    for (int r = 0; r < 4; ++r) { zaccA[j*4+r] = 0.f; zaccB[j*4+r] = 0.f; }
    uint2 pa; pa.x = pk2(va.x, va.y); pa.y = pk2(va.z, va.w);
    uint2 pb; pb.x = pk2(vb.x, vb.y); pb.y = pk2(vb.z, vb.w);
    *(uint2*)&ZbufA[zw0 + nt * 1024] = pa;
    *(uint2*)&ZbufB[zw0 + nt * 1024] = pb;
  }

  const float DT6 = DT / 6.0f, DT3 = DT / 3.0f, DTH = 0.5f * DT;

  floatx4 accA[2][4], accB[2][4];

  // ---- helpers ----
  // one-eighth of an epilogue: 4 tanh + 2 packs + 1 b64 write (conflict-free)
  auto ePart = [&](int u, floatx4 (&a)[2][4], unsigned short* H) {
    const int tt = u >> 2, nt = u & 3;
    uint2 p;
    p.x = pk2(tanh_pre(a[tt][nt][0]), tanh_pre(a[tt][nt][1]));
    p.y = pk2(tanh_pre(a[tt][nt][2]), tanh_pre(a[tt][nt][3]));
    *(uint2*)&H[hw0 + tt * 384 + nt * 6144] = p;
  };
  // one step of L1 (pair u: s=u>>2, nt=u&3): 2 MFMAs; s==0 seeds bias-C
  auto p1Step = [&](int u, const unsigned short* Z, floatx4 (&a)[2][4]) {
    const int s = u >> 2, nt = u & 3;
    short8 bz = *(const short8*)&Z[rb + (nt * 2 + s) * 512];
    if (s == 0) {
      a[0][nt] = __builtin_amdgcn_mfma_f32_16x16x32_bf16(w1f[0][0], bz, b1f[0], 0, 0, 0);
      a[1][nt] = __builtin_amdgcn_mfma_f32_16x16x32_bf16(w1f[0][1], bz, b1f[1], 0, 0, 0);
    } else {
      a[0][nt] = __builtin_amdgcn_mfma_f32_16x16x32_bf16(w1f[1][0], bz, a[0][nt], 0, 0, 0);
      a[1][nt] = __builtin_amdgcn_mfma_f32_16x16x32_bf16(w1f[1][1], bz, a[1][nt], 0, 0, 0);
    }
  };
  // one s-step of L3: 2 MFMAs; s==0 seeds bias-C
  auto p3Step = [&](int s, const unsigned short* H, floatx4 (&a3)[2]) {
    short8 b0 = ldH(&H[rbH + (ntp * 16 + s) * 768]);
    short8 b1_ = ldH(&H[rbH + (ntp * 16 + 8 + s) * 768]);
    if (s == 0) {
      a3[0] = __builtin_amdgcn_mfma_f32_16x16x32_bf16(w3f[0], b0, b3f, 0, 0, 0);
      a3[1] = __builtin_amdgcn_mfma_f32_16x16x32_bf16(w3f[0], b1_, b3f, 0, 0, 0);
    } else {
      a3[0] = __builtin_amdgcn_mfma_f32_16x16x32_bf16(w3f[s], b0, a3[0], 0, 0, 0);
      a3[1] = __builtin_amdgcn_mfma_f32_16x16x32_bf16(w3f[s], b1_, a3[1], 0, 0, 0);
    }
  };
  auto rk4Tail = [&](floatx4 (&a3)[2], float (&z)[8], float (&zacc)[8],
                     unsigned short* Z, int st) {
    const float wsum  = (st == 0 || st == 3) ? DT6 : DT3;
    const float cst   = (st == 2) ? DT : DTH;
    const bool  last  = (st == 3);
    const bool  first = (st == 0);
#pragma unroll
    for (int j = 0; j < 2; ++j) {
      const int nt = 2 * ntp + j;
      float stg[4];
#pragma unroll
      for (int r = 0; r < 4; ++r) {
        const int i = j * 4 + r;
        float k = a3[j][r];
        float za = first ? z[i] : zacc[i];
        za += wsum * k;
        zacc[i] = za;
        if (last) { z[i] = za; stg[r] = za; }
        else      { stg[r] = z[i] + cst * k; }
      }
      uint2 p; p.x = pk2(stg[0], stg[1]); p.y = pk2(stg[2], stg[3]);
      *(uint2*)&Z[zw0 + nt * 1024] = p;
    }
  };

  // ---- prologue: advance B through P1,E1,P2,E2 of stage 0 (unfused) ----
  __syncthreads();                 // Zbuf init visible
#pragma unroll
  for (int u = 0; u < 8; ++u) p1Step(u, ZbufB, accB);
#pragma unroll
  for (int u = 0; u < 8; ++u) ePart(u, accB, HbufB);
  __syncthreads();
#pragma unroll
  for (int s = 0; s < 8; ++s)
#pragma unroll
    for (int nt = 0; nt < 4; ++nt) {
      short8 bh = ldH(&HbufB[rbH + (nt * 8 + s) * 768]);
      accB[0][nt] = __builtin_amdgcn_mfma_f32_16x16x32_bf16(w2f[s][0], bh,
                      s == 0 ? b2f[0] : accB[0][nt], 0, 0, 0);
      accB[1][nt] = __builtin_amdgcn_mfma_f32_16x16x32_bf16(w2f[s][1], bh,
                      s == 0 ? b2f[1] : accB[1][nt], 0, 0, 0);
    }
  __syncthreads();
#pragma unroll
  for (int u = 0; u < 8; ++u) ePart(u, accB, HbufB);
  __syncthreads();

  // ---- steady state: 5 intervals per it, MFMA⇄VALU fused per step ----
#pragma unroll 1
  for (int it = 0; it < NSTEPS * 4; ++it) {
    const int st = it & 3;

    // k=0: A:P1 (16 MFMA) fused with B:P3 (16 MFMA) + B RK4 tail
    {
      floatx4 a3[2];
#pragma unroll
      for (int u = 0; u < 8; ++u) {
        p3Step(u, HbufB, a3);
        p1Step(u, ZbufA, accA);
      }
      rk4Tail(a3, zB, zaccB, ZbufB, st);
    }
    __syncthreads();

    // k=1: B:P1 (16 MFMA) fused with A:E1 (32 tanh)
    {
#pragma unroll
      for (int u = 0; u < 8; ++u) {
        p1Step(u, ZbufB, accB);
        ePart(u, accA, HbufA);
      }
    }
    __syncthreads();

    // k=2: A:P2 (64 MFMA) fused with B:E1 (32 tanh)
    {
#pragma unroll
      for (int s = 0; s < 8; ++s) {
#pragma unroll
        for (int nt = 0; nt < 4; ++nt) {
          short8 bh = ldH(&HbufA[rbH + (nt * 8 + s) * 768]);
          accA[0][nt] = __builtin_amdgcn_mfma_f32_16x16x32_bf16(w2f[s][0], bh,
                          s == 0 ? b2f[0] : accA[0][nt], 0, 0, 0);
          accA[1][nt] = __builtin_amdgcn_mfma_f32_16x16x32_bf16(w2f[s][1], bh,
                          s == 0 ? b2f[1] : accA[1][nt], 0, 0, 0);
        }
        ePart(s, accB, HbufB);
      }
    }
    __syncthreads();

    // k=3: B:P2 (64 MFMA) fused with A:E2 (32 tanh)
    {
#pragma unroll
      for (int s = 0; s < 8; ++s) {
#pragma unroll
        for (int nt = 0; nt < 4; ++nt) {
          short8 bh = ldH(&HbufB[rbH + (nt * 8 + s) * 768]);
          accB[0][nt] = __builtin_amdgcn_mfma_f32_16x16x32_bf16(w2f[s][0], bh,
                          s == 0 ? b2f[0] : accB[0][nt], 0, 0, 0);
          accB[1][nt] = __builtin_amdgcn_mfma_f32_16x16x32_bf16(w2f[s][1], bh,
                          s == 0 ? b2f[1] : accB[1][nt], 0, 0, 0);
        }
        ePart(s, accA, HbufA);
      }
    }
    __syncthreads();

    // k=4: A:P3 (16 MFMA) + A RK4, fused with B:E2 (32 tanh)
    {
      floatx4 a3[2];
#pragma unroll
      for (int u = 0; u < 8; ++u) {
        p3Step(u, HbufA, a3);
        ePart(u, accB, HbufB);
      }
      rk4Tail(a3, zA, zaccA, ZbufA, st);
    }
    __syncthreads();
  }
  // (B's trailing stage-400 P1/P2/E work never runs P3, so zB is final.)

  // ---- final store, both groups ----
#pragma unroll
  for (int j = 0; j < 2; ++j) {
    const int nt = 2 * ntp + j;
    float4 va, vb;
    va.x = zA[j*4+0]; va.y = zA[j*4+1]; va.z = zA[j*4+2]; va.w = zA[j*4+3];
    vb.x = zB[j*4+0]; vb.y = zB[j*4+1]; vb.z = zB[j*4+2]; vb.w = zB[j*4+3];
    *(float4*)&out[(grow + nt * 16 + i15) * 64 + mt3 * 16 + q * 4] = va;
    *(float4*)&out[(grow + 64 + nt * 16 + i15) * 64 + mt3 * 16 + q * 4] = vb;
  }
}

extern "C" void kernel_launch(void* const* d_in, const int* in_sizes, int n_in,
                              void* d_out, int out_size, void* d_ws, size_t ws_size,
                              hipStream_t stream) {
  const float* z0 = (const float*)d_in[0];
  const float* W1 = (const float*)d_in[1];
  const float* b1 = (const float*)d_in[2];
  const float* W2 = (const float*)d_in[3];
  const float* b2 = (const float*)d_in[4];
  const float* W3 = (const float*)d_in[5];
  const float* b3 = (const float*)d_in[6];
  unsigned short* ws = (unsigned short*)d_ws;  // 98304 bf16 = 196608 B

  prep_weights<<<384, 256, 0, stream>>>(W1, W2, W3, ws);
  (void)hipFuncSetAttribute((const void*)cnf_kernel,
                            hipFuncAttributeMaxDynamicSharedMemorySize, 114688);
  cnf_kernel<<<256, 512, 114688, stream>>>(z0, b1, b2, b3, ws, (float*)d_out);
}

// Round 10
// 2843.870 us; speedup vs baseline: 1.2102x; 1.0467x over previous
//
#include <hip/hip_runtime.h>
#include <hip/hip_bf16.h>

#define NSTEPS 100
#define DT (1.0f / 100.0f)
#define TSCALE 2.885390081777927f   // 2*log2(e): folded into W1,W2,b1,b2

typedef __attribute__((ext_vector_type(8))) short short8;   // 8 bf16 (MFMA A/B frag)
typedef __attribute__((ext_vector_type(4))) float floatx4;  // MFMA C/D frag

__device__ __forceinline__ unsigned short f2bf(float f) {
  union { float f; unsigned int u; } v; v.f = f;
  unsigned int u = v.u;
  return (unsigned short)((u + 0x7fffu + ((u >> 16) & 1u)) >> 16);  // RNE
}
__device__ __forceinline__ unsigned int pk2(float a, float b) {
  __hip_bfloat162 h = __float22bfloat162_rn(make_float2(a, b));
  union { __hip_bfloat162 h; unsigned int u; } v; v.h = h;
  return v.u;
}
// tanh with input pre-scaled by 2*log2(e): tanh = 1 - 2/(2^y + 1)
__device__ __forceinline__ float tanh_pre(float y) {
  float e = __builtin_amdgcn_exp2f(y);
  return 1.0f - 2.0f * __builtin_amdgcn_rcpf(e + 1.0f);
}

// Repack W (K x N row-major fp32) into frag-major bf16 (A-frag of W^T).
// W1/W2 are pre-scaled by TSCALE (tanh input scale folded in).
// R9: W2/W3 use the pi-permuted k mapping (swap k-bit4 <-> k-bit2 within
// each 32-k-slice). H is stored pi-permuted so each lane's 8 epilogue
// values form ONE 16B line (b128 write, conflict-free); applying the SAME
// uniform permutation to the A-operand (here) keeps MFMA results exact.
// W1 keeps the identity mapping (its B-source Zbuf is not permuted).
__global__ void prep_weights(const float* __restrict__ W1,
                             const float* __restrict__ W2,
                             const float* __restrict__ W3,
                             unsigned short* __restrict__ ws) {
  int e = blockIdx.x * 256 + threadIdx.x;  // 98304 total
  const float* src; int N, ntile, el, base; float sc;
  if (e < 16384)      { src = W1; N = 256; ntile = 16; base = 0;     el = e;         sc = TSCALE; }
  else if (e < 81920) { src = W2; N = 256; ntile = 16; base = 16384; el = e - 16384; sc = TSCALE; }
  else                { src = W3; N = 64;  ntile = 4;  base = 81920; el = e - 81920; sc = 1.0f; }
  int j = el & 7;
  int l = (el >> 3) & 63;
  int rem = el >> 9;
  int t = rem % ntile;
  int s = rem / ntile;
  int k;
  if (e < 16384) {
    k = s * 32 + ((l >> 4) << 3) + j;                       // identity (W1)
  } else {
    // pi: k = 16*b(j,2) + 8*b(l,4) + 4*b(l,5) + (j&3)      (W2, W3)
    k = s * 32 + 16 * ((j >> 2) & 1) + 8 * ((l >> 4) & 1) + 4 * ((l >> 5) & 1) + (j & 3);
  }
  int n = t * 16 + (l & 15);
  ws[base + el] = f2bf(src[k * N + n] * sc);
}

// R9 = R5 (5-phase dual-group, weights register-resident, 2642-2709 us)
// + pi-permuted H layout -> b128 epilogue writes.
// R5's SQ_LDS_BANK_CONFLICT=1.181e8 was exactly the 8B H/Z writes (2-way
// in each 16-lane phase). 8B writes at 16B-aligned strides are provably
// stuck (R6 data-swizzle unsound, R8 24B stride spilled). Fix: permute k
// within each 32-slice (swap bit4<->bit2, uniform across lanes) so a
// lane's 8 values (tt=0,1 x r=0..3) occupy ONE line: line=16*(2(q&1)+
// (q>>1))+i15, elems 4tt+r. One b128 write/lane/nt: bank pattern = the
// b128 reads' (measured ~0 conflicts in R8). Readers unchanged; W2/W3
// A-frags pi'd in prep (zero kernel cost). Zbuf/W1 path untouched
// (residual conflicts ~1.3e7). No new registers.
__global__ __launch_bounds__(512, 2)
void cnf_kernel(const float* __restrict__ z0,
                const float* __restrict__ b1,
                const float* __restrict__ b2,
                const float* __restrict__ b3,
                const unsigned short* __restrict__ wsAll,
                float* __restrict__ out) {
  extern __shared__ unsigned short smem[];   // 81920 B
  unsigned short* ZbufA = smem;              //  8192 B (4 nt * 2 s * 512)
  unsigned short* ZbufB = smem + 4096;
  unsigned short* HbufA = smem + 8192;       // 32768 B (4 nt * 8 s * 512)
  unsigned short* HbufB = smem + 24576;

  const int tid  = threadIdx.x;
  const int wave = tid >> 6;
  const int lane = tid & 63;
  const int i15  = lane & 15;
  const int q    = lane >> 4;
  const int grow = blockIdx.x * 128;         // group A rows; B = +64
  const int mt3  = wave & 3;                 // L3 M-tile
  const int ntp  = wave >> 2;                // L3 N-pair

  const unsigned short* wsW1 = wsAll;
  const unsigned short* wsW2 = wsAll + 16384;
  const unsigned short* wsW3 = wsAll + 81920;

  // ---- register-resident weight A-frags ----
  short8 w1f[2][2];
#pragma unroll
  for (int s = 0; s < 2; ++s)
#pragma unroll
    for (int tt = 0; tt < 2; ++tt)
      w1f[s][tt] = *(const short8*)&wsW1[((s * 16 + 2 * wave + tt) * 64 + lane) * 8];
  short8 w2f[8][2];
#pragma unroll
  for (int s = 0; s < 8; ++s)
#pragma unroll
    for (int tt = 0; tt < 2; ++tt)
      w2f[s][tt] = *(const short8*)&wsW2[((s * 16 + 2 * wave + tt) * 64 + lane) * 8];
  short8 w3f[8];
#pragma unroll
  for (int s = 0; s < 8; ++s)
    w3f[s] = *(const short8*)&wsW3[((s * 4 + mt3) * 64 + lane) * 8];

  // ---- bias C-frags (fp32); b1/b2 pre-scaled by TSCALE ----
  floatx4 b1f[2], b2f[2], b3f;
#pragma unroll
  for (int tt = 0; tt < 2; ++tt) {
    float4 v1 = *(const float4*)&b1[(2 * wave + tt) * 16 + q * 4];
    float4 v2 = *(const float4*)&b2[(2 * wave + tt) * 16 + q * 4];
    b1f[tt] = floatx4{v1.x * TSCALE, v1.y * TSCALE, v1.z * TSCALE, v1.w * TSCALE};
    b2f[tt] = floatx4{v2.x * TSCALE, v2.y * TSCALE, v2.z * TSCALE, v2.w * TSCALE};
  }
  {
    float4 v3 = *(const float4*)&b3[mt3 * 16 + q * 4];
    b3f = floatx4{v3.x, v3.y, v3.z, v3.w};
  }

  // ---- frag-layout index bases ----
  const int rb  = lane * 8;                                   // act read base; tile adds *512
  const int j0  = 4 * (q & 1);
  // H write: pi'd line = 16*(2(q&1)+(q>>1)) + i15, full 16B; +nt*4096
  const int cp  = 2 * (q & 1) + (q >> 1);
  const int hw0 = wave * 512 + (16 * cp + i15) * 8;
  const int zw0 = ((mt3 >> 1) * 64 + i15 + 16 * (2 * (mt3 & 1) + (q >> 1))) * 8 + j0;  // +nt*1024

  // ---- RK4 state, both groups ----
  float zA[8], zaccA[8], zB[8], zaccB[8];
#pragma unroll
  for (int j = 0; j < 2; ++j) {
    const int nt = 2 * ntp + j;
    float4 va = *(const float4*)&z0[(grow + nt * 16 + i15) * 64 + mt3 * 16 + q * 4];
    float4 vb = *(const float4*)&z0[(grow + 64 + nt * 16 + i15) * 64 + mt3 * 16 + q * 4];
    zA[j*4+0]=va.x; zA[j*4+1]=va.y; zA[j*4+2]=va.z; zA[j*4+3]=va.w;
    zB[j*4+0]=vb.x; zB[j*4+1]=vb.y; zB[j*4+2]=vb.z; zB[j*4+3]=vb.w;
#pragma unroll
    for (int r = 0; r < 4; ++r) { zaccA[j*4+r] = 0.f; zaccB[j*4+r] = 0.f; }
    uint2 pa; pa.x = pk2(va.x, va.y); pa.y = pk2(va.z, va.w);
    uint2 pb; pb.x = pk2(vb.x, vb.y); pb.y = pk2(vb.z, vb.w);
    *(uint2*)&ZbufA[zw0 + nt * 1024] = pa;
    *(uint2*)&ZbufB[zw0 + nt * 1024] = pb;
  }

  const float DT6 = DT / 6.0f, DT3 = DT / 3.0f, DTH = 0.5f * DT;

  floatx4 accA[2][4], accB[2][4];

  // ---- helpers ----
  // one-quarter of an epilogue: 8 tanh + 4 packs + 1 b128 write
  auto ePartLine = [&](int nt, floatx4 (&a)[2][4], unsigned short* H) {
    uint4 p;
    p.x = pk2(tanh_pre(a[0][nt][0]), tanh_pre(a[0][nt][1]));
    p.y = pk2(tanh_pre(a[0][nt][2]), tanh_pre(a[0][nt][3]));
    p.z = pk2(tanh_pre(a[1][nt][0]), tanh_pre(a[1][nt][1]));
    p.w = pk2(tanh_pre(a[1][nt][2]), tanh_pre(a[1][nt][3]));
    *(uint4*)&H[hw0 + nt * 4096] = p;
  };
  // one step of L1 (pair u: s=u>>2, nt=u&3): 2 MFMAs; s==0 seeds bias-C
  auto p1Step = [&](int u, const unsigned short* Z, floatx4 (&a)[2][4]) {
    const int s = u >> 2, nt = u & 3;
    short8 bz = *(const short8*)&Z[rb + (nt * 2 + s) * 512];
    if (s == 0) {
      a[0][nt] = __builtin_amdgcn_mfma_f32_16x16x32_bf16(w1f[0][0], bz, b1f[0], 0, 0, 0);
      a[1][nt] = __builtin_amdgcn_mfma_f32_16x16x32_bf16(w1f[0][1], bz, b1f[1], 0, 0, 0);
    } else {
      a[0][nt] = __builtin_amdgcn_mfma_f32_16x16x32_bf16(w1f[1][0], bz, a[0][nt], 0, 0, 0);
      a[1][nt] = __builtin_amdgcn_mfma_f32_16x16x32_bf16(w1f[1][1], bz, a[1][nt], 0, 0, 0);
    }
  };
  // one s-step of L3: 2 MFMAs; s==0 seeds bias-C
  auto p3Step = [&](int s, const unsigned short* H, floatx4 (&a3)[2]) {
    short8 b0 = *(const short8*)&H[rb + (ntp * 16 + s) * 512];
    short8 b1_ = *(const short8*)&H[rb + (ntp * 16 + 8 + s) * 512];
    if (s == 0) {
      a3[0] = __builtin_amdgcn_mfma_f32_16x16x32_bf16(w3f[0], b0, b3f, 0, 0, 0);
      a3[1] = __builtin_amdgcn_mfma_f32_16x16x32_bf16(w3f[0], b1_, b3f, 0, 0, 0);
    } else {
      a3[0] = __builtin_amdgcn_mfma_f32_16x16x32_bf16(w3f[s], b0, a3[0], 0, 0, 0);
      a3[1] = __builtin_amdgcn_mfma_f32_16x16x32_bf16(w3f[s], b1_, a3[1], 0, 0, 0);
    }
  };
  auto rk4Tail = [&](floatx4 (&a3)[2], float (&z)[8], float (&zacc)[8],
                     unsigned short* Z, int st) {
    const float wsum  = (st == 0 || st == 3) ? DT6 : DT3;
    const float cst   = (st == 2) ? DT : DTH;
    const bool  last  = (st == 3);
    const bool  first = (st == 0);
#pragma unroll
    for (int j = 0; j < 2; ++j) {
      const int nt = 2 * ntp + j;
      float stg[4];
#pragma unroll
      for (int r = 0; r < 4; ++r) {
        const int i = j * 4 + r;
        float k = a3[j][r];
        float za = first ? z[i] : zacc[i];
        za += wsum * k;
        zacc[i] = za;
        if (last) { z[i] = za; stg[r] = za; }
        else      { stg[r] = z[i] + cst * k; }
      }
      uint2 p; p.x = pk2(stg[0], stg[1]); p.y = pk2(stg[2], stg[3]);
      *(uint2*)&Z[zw0 + nt * 1024] = p;
    }
  };

  // ---- prologue: advance B through P1,E1,P2,E2 of stage 0 (unfused) ----
  __syncthreads();                 // Zbuf init visible
#pragma unroll
  for (int u = 0; u < 8; ++u) p1Step(u, ZbufB, accB);
#pragma unroll
  for (int nt = 0; nt < 4; ++nt) ePartLine(nt, accB, HbufB);
  __syncthreads();
#pragma unroll
  for (int s = 0; s < 8; ++s)
#pragma unroll
    for (int nt = 0; nt < 4; ++nt) {
      short8 bh = *(const short8*)&HbufB[rb + (nt * 8 + s) * 512];
      accB[0][nt] = __builtin_amdgcn_mfma_f32_16x16x32_bf16(w2f[s][0], bh,
                      s == 0 ? b2f[0] : accB[0][nt], 0, 0, 0);
      accB[1][nt] = __builtin_amdgcn_mfma_f32_16x16x32_bf16(w2f[s][1], bh,
                      s == 0 ? b2f[1] : accB[1][nt], 0, 0, 0);
    }
  __syncthreads();
#pragma unroll
  for (int nt = 0; nt < 4; ++nt) ePartLine(nt, accB, HbufB);
  __syncthreads();

  // ---- steady state: 5 intervals per it, MFMA⇄VALU fused per step ----
#pragma unroll 1
  for (int it = 0; it < NSTEPS * 4; ++it) {
    const int st = it & 3;

    // k=0: A:P1 (16 MFMA) fused with B:P3 (16 MFMA) + B RK4 tail
    {
      floatx4 a3[2];
#pragma unroll
      for (int u = 0; u < 8; ++u) {
        p3Step(u, HbufB, a3);
        p1Step(u, ZbufA, accA);
      }
      rk4Tail(a3, zB, zaccB, ZbufB, st);
    }
    __syncthreads();

    // k=1: B:P1 (16 MFMA) fused with A:E1 (32 tanh, 4 b128 writes)
    {
#pragma unroll
      for (int u = 0; u < 8; ++u) {
        p1Step(u, ZbufB, accB);
        if (u & 1) ePartLine(u >> 1, accA, HbufA);
      }
    }
    __syncthreads();

    // k=2: A:P2 (64 MFMA) fused with B:E1 (32 tanh, 4 b128 writes)
    {
#pragma unroll
      for (int s = 0; s < 8; ++s) {
#pragma unroll
        for (int nt = 0; nt < 4; ++nt) {
          short8 bh = *(const short8*)&HbufA[rb + (nt * 8 + s) * 512];
          accA[0][nt] = __builtin_amdgcn_mfma_f32_16x16x32_bf16(w2f[s][0], bh,
                          s == 0 ? b2f[0] : accA[0][nt], 0, 0, 0);
          accA[1][nt] = __builtin_amdgcn_mfma_f32_16x16x32_bf16(w2f[s][1], bh,
                          s == 0 ? b2f[1] : accA[1][nt], 0, 0, 0);
        }
        if (s & 1) ePartLine(s >> 1, accB, HbufB);
      }
    }
    __syncthreads();

    // k=3: B:P2 (64 MFMA) fused with A:E2 (32 tanh, 4 b128 writes)
    {
#pragma unroll
      for (int s = 0; s < 8; ++s) {
#pragma unroll
        for (int nt = 0; nt < 4; ++nt) {
          short8 bh = *(const short8*)&HbufB[rb + (nt * 8 + s) * 512];
          accB[0][nt] = __builtin_amdgcn_mfma_f32_16x16x32_bf16(w2f[s][0], bh,
                          s == 0 ? b2f[0] : accB[0][nt], 0, 0, 0);
          accB[1][nt] = __builtin_amdgcn_mfma_f32_16x16x32_bf16(w2f[s][1], bh,
                          s == 0 ? b2f[1] : accB[1][nt], 0, 0, 0);
        }
        if (s & 1) ePartLine(s >> 1, accA, HbufA);
      }
    }
    __syncthreads();

    // k=4: A:P3 (16 MFMA) + A RK4, fused with B:E2 (32 tanh, 4 b128 writes)
    {
      floatx4 a3[2];
#pragma unroll
      for (int u = 0; u < 8; ++u) {
        p3Step(u, HbufA, a3);
        if (u & 1) ePartLine(u >> 1, accB, HbufB);
      }
      rk4Tail(a3, zA, zaccA, ZbufA, st);
    }
    __syncthreads();
  }
  // (B's trailing stage-400 P1/P2/E work never runs P3, so zB is final.)

  // ---- final store, both groups ----
#pragma unroll
  for (int j = 0; j < 2; ++j) {
    const int nt = 2 * ntp + j;
    float4 va, vb;
    va.x = zA[j*4+0]; va.y = zA[j*4+1]; va.z = zA[j*4+2]; va.w = zA[j*4+3];
    vb.x = zB[j*4+0]; vb.y = zB[j*4+1]; vb.z = zB[j*4+2]; vb.w = zB[j*4+3];
    *(float4*)&out[(grow + nt * 16 + i15) * 64 + mt3 * 16 + q * 4] = va;
    *(float4*)&out[(grow + 64 + nt * 16 + i15) * 64 + mt3 * 16 + q * 4] = vb;
  }
}

extern "C" void kernel_launch(void* const* d_in, const int* in_sizes, int n_in,
                              void* d_out, int out_size, void* d_ws, size_t ws_size,
                              hipStream_t stream) {
  const float* z0 = (const float*)d_in[0];
  const float* W1 = (const float*)d_in[1];
  const float* b1 = (const float*)d_in[2];
  const float* W2 = (const float*)d_in[3];
  const float* b2 = (const float*)d_in[4];
  const float* W3 = (const float*)d_in[5];
  const float* b3 = (const float*)d_in[6];
  unsigned short* ws = (unsigned short*)d_ws;  // 98304 bf16 = 196608 B

  prep_weights<<<384, 256, 0, stream>>>(W1, W2, W3, ws);
  (void)hipFuncSetAttribute((const void*)cnf_kernel,
                            hipFuncAttributeMaxDynamicSharedMemorySize, 81920);
  cnf_kernel<<<256, 512, 81920, stream>>>(z0, b1, b2, b3, ws, (float*)d_out);
}